// Round 4
// baseline (57.936 us; speedup 1.0000x reference)
//
#include <hip/hip_runtime.h>
#include <hip/hip_bf16.h>
#include <math.h>

#define EPS 1e-10f

typedef float floatx4 __attribute__((ext_vector_type(4)));

// Monotone map float -> uint preserving order (for packed argmax keys).
__device__ __forceinline__ unsigned int ordf(float f) {
    unsigned int b = __float_as_uint(f);
    return (b & 0x80000000u) ? ~b : (b | 0x80000000u);
}

// Fused sampler: grid = S segments x (B/R) rowgroups, 256 threads (4 waves).
// Block (seg,rowg): stage logE[segment] into LDS once, then each wave streams
// R/4 rows of logits over the segment computing argmax of
//   greedy (t==0):  logits[j]
//   sampled:        logits[j]*(1/t) - log(E[j]+EPS)
// Partials merged across blocks via atomicMax on packed (ordval<<32 | ~idx)
// keys (max == argmax, ties -> lowest index). Last block converts keys -> out.
__global__ __launch_bounds__(256) void fused_sampler_kernel(
    const float* __restrict__ logits,
    const float* __restrict__ temps,
    const float* __restrict__ expo,
    int* __restrict__ out,
    unsigned long long* __restrict__ keys,  // [B], memset 0 per launch
    unsigned int* __restrict__ ctr,         // [1],  memset 0 per launch
    int B, int V, int S, int segLen, int R) {

    extern __shared__ __align__(16) float sE[];   // segLen floats

    const int bid     = blockIdx.x;
    const int seg     = bid % S;
    const int rowBase = (bid / S) * R;
    const int tid     = threadIdx.x;
    const int wave    = tid >> 6;
    const int lane    = tid & 63;

    const int beg  = seg * segLen;
    const int end  = min(beg + segLen, V);
    const int segN = end - beg;

    // Stage log(E+eps) for this segment iff any row here is sampled.
    bool anySampled = false;
    for (int r = 0; r < R; ++r) {
        int row = rowBase + r;
        if (row < B && temps[row] != 0.0f) anySampled = true;
    }
    if (anySampled) {
        for (int j = tid; j < segN; j += 256)
            sE[j] = logf(expo[beg + j] + EPS);
    }
    __syncthreads();

    const int beg4 = beg >> 2;     // segLen % 4 == 0, V % 4 == 0
    const int end4 = end >> 2;
    const floatx4* sE4 = reinterpret_cast<const floatx4*>(sE);

    const int rowsPerWave = R >> 2;  // 4 waves per block
    for (int rr = 0; rr < rowsPerWave; ++rr) {
        const int row = rowBase + wave + (rr << 2);
        if (row >= B) continue;

        const float t = temps[row];                 // wave-uniform
        const bool greedy = (t == 0.0f);
        const float inv_t = greedy ? 1.0f : (1.0f / t);
        const floatx4* rl4 =
            reinterpret_cast<const floatx4*>(logits + (size_t)row * (size_t)V);

        float best = -INFINITY;
        int   bidx = 0x7fffffff;

        int i = beg4 + lane;
        if (greedy) {
            for (; i + 64 < end4; i += 128) {          // unroll x2
                floatx4 a = rl4[i];
                floatx4 b = rl4[i + 64];
                int ab = i << 2, bb = (i + 64) << 2;
                if (a.x > best) { best = a.x; bidx = ab;     }
                if (a.y > best) { best = a.y; bidx = ab + 1; }
                if (a.z > best) { best = a.z; bidx = ab + 2; }
                if (a.w > best) { best = a.w; bidx = ab + 3; }
                if (b.x > best) { best = b.x; bidx = bb;     }
                if (b.y > best) { best = b.y; bidx = bb + 1; }
                if (b.z > best) { best = b.z; bidx = bb + 2; }
                if (b.w > best) { best = b.w; bidx = bb + 3; }
            }
            for (; i < end4; i += 64) {
                floatx4 a = rl4[i];
                int ab = i << 2;
                if (a.x > best) { best = a.x; bidx = ab;     }
                if (a.y > best) { best = a.y; bidx = ab + 1; }
                if (a.z > best) { best = a.z; bidx = ab + 2; }
                if (a.w > best) { best = a.w; bidx = ab + 3; }
            }
        } else {
            for (; i + 64 < end4; i += 128) {          // unroll x2
                floatx4 a  = rl4[i];
                floatx4 b  = rl4[i + 64];
                floatx4 ga = sE4[i - beg4];
                floatx4 gb = sE4[i + 64 - beg4];
                int ab = i << 2, bb = (i + 64) << 2;
                float s;
                s = fmaf(a.x, inv_t, -ga.x); if (s > best) { best = s; bidx = ab;     }
                s = fmaf(a.y, inv_t, -ga.y); if (s > best) { best = s; bidx = ab + 1; }
                s = fmaf(a.z, inv_t, -ga.z); if (s > best) { best = s; bidx = ab + 2; }
                s = fmaf(a.w, inv_t, -ga.w); if (s > best) { best = s; bidx = ab + 3; }
                s = fmaf(b.x, inv_t, -gb.x); if (s > best) { best = s; bidx = bb;     }
                s = fmaf(b.y, inv_t, -gb.y); if (s > best) { best = s; bidx = bb + 1; }
                s = fmaf(b.z, inv_t, -gb.z); if (s > best) { best = s; bidx = bb + 2; }
                s = fmaf(b.w, inv_t, -gb.w); if (s > best) { best = s; bidx = bb + 3; }
            }
            for (; i < end4; i += 64) {
                floatx4 a  = rl4[i];
                floatx4 ga = sE4[i - beg4];
                int ab = i << 2;
                float s;
                s = fmaf(a.x, inv_t, -ga.x); if (s > best) { best = s; bidx = ab;     }
                s = fmaf(a.y, inv_t, -ga.y); if (s > best) { best = s; bidx = ab + 1; }
                s = fmaf(a.z, inv_t, -ga.z); if (s > best) { best = s; bidx = ab + 2; }
                s = fmaf(a.w, inv_t, -ga.w); if (s > best) { best = s; bidx = ab + 3; }
            }
        }

        // Wave reduce (64 lanes), prefer lower index on exact ties.
        #pragma unroll
        for (int off = 32; off >= 1; off >>= 1) {
            float ov = __shfl_down(best, off);
            int   oi = __shfl_down(bidx, off);
            if (ov > best || (ov == best && oi < bidx)) { best = ov; bidx = oi; }
        }
        if (lane == 0) {
            unsigned long long key =
                ((unsigned long long)ordf(best) << 32) | (unsigned int)(~bidx);
            atomicMax(&keys[row], key);
        }
    }

    // Last block converts keys -> out (device-scope atomics + fences).
    __syncthreads();
    __shared__ int sLast;
    if (tid == 0) {
        __threadfence();
        unsigned int old = atomicAdd(ctr, 1u);
        sLast = (old == (unsigned int)(gridDim.x - 1)) ? 1 : 0;
    }
    __syncthreads();
    if (sLast) {
        for (int r = tid; r < B; r += 256) {
            unsigned long long k = atomicMax(&keys[r], 0ULL);  // coherent read
            out[r] = (int)(~(unsigned int)(k & 0xFFFFFFFFull));
        }
    }
}

// Fallback: one block per row, on-the-fly log, writes out directly.
__global__ __launch_bounds__(1024) void row_argmax_kernel(
    const float* __restrict__ logits,
    const float* __restrict__ temps,
    const float* __restrict__ expo,
    int* __restrict__ out, int V) {
    const int row = blockIdx.x;
    const float t = temps[row];
    const bool greedy = (t == 0.0f);
    const float inv_t = greedy ? 1.0f : (1.0f / t);
    const floatx4* rl4 = reinterpret_cast<const floatx4*>(logits + (size_t)row * (size_t)V);
    const floatx4* e4  = reinterpret_cast<const floatx4*>(expo);
    float best = -INFINITY; int bidx = 0x7fffffff;
    const int nvec = V >> 2;
    for (int i = threadIdx.x; i < nvec; i += blockDim.x) {
        floatx4 l = rl4[i];
        float s0, s1, s2, s3;
        if (greedy) { s0 = l.x; s1 = l.y; s2 = l.z; s3 = l.w; }
        else {
            floatx4 g = e4[i];
            s0 = fmaf(l.x, inv_t, -logf(g.x + EPS));
            s1 = fmaf(l.y, inv_t, -logf(g.y + EPS));
            s2 = fmaf(l.z, inv_t, -logf(g.z + EPS));
            s3 = fmaf(l.w, inv_t, -logf(g.w + EPS));
        }
        int base = i << 2;
        if (s0 > best) { best = s0; bidx = base;     }
        if (s1 > best) { best = s1; bidx = base + 1; }
        if (s2 > best) { best = s2; bidx = base + 2; }
        if (s3 > best) { best = s3; bidx = base + 3; }
    }
    #pragma unroll
    for (int off = 32; off >= 1; off >>= 1) {
        float ov = __shfl_down(best, off);
        int   oi = __shfl_down(bidx, off);
        if (ov > best || (ov == best && oi < bidx)) { best = ov; bidx = oi; }
    }
    __shared__ float sv[16];
    __shared__ int   si[16];
    const int wid = threadIdx.x >> 6, lane = threadIdx.x & 63, nw = blockDim.x >> 6;
    if (lane == 0) { sv[wid] = best; si[wid] = bidx; }
    __syncthreads();
    if (wid == 0) {
        best = (lane < nw) ? sv[lane] : -INFINITY;
        bidx = (lane < nw) ? si[lane] : 0x7fffffff;
        #pragma unroll
        for (int off = 8; off >= 1; off >>= 1) {
            float ov = __shfl_down(best, off);
            int   oi = __shfl_down(bidx, off);
            if (ov > best || (ov == best && oi < bidx)) { best = ov; bidx = oi; }
        }
        if (lane == 0) out[row] = bidx;
    }
}

extern "C" void kernel_launch(void* const* d_in, const int* in_sizes, int n_in,
                              void* d_out, int out_size, void* d_ws, size_t ws_size,
                              hipStream_t stream) {
    const float* logits = (const float*)d_in[0];
    const float* temps  = (const float*)d_in[1];
    const float* expo   = (const float*)d_in[2];
    int*         out    = (int*)d_out;

    const int B = in_sizes[1];
    const int V = in_sizes[2];

    const int S = 32;
    const int R = 8;
    const int segLen = (((V + S - 1) / S) + 3) & ~3;      // multiple of 4
    const size_t smem = (size_t)segLen * sizeof(float);
    const size_t need = (size_t)B * 8 + 64;

    if (ws_size >= need && smem <= 64 * 1024 && (V & 3) == 0) {
        unsigned long long* keys = (unsigned long long*)d_ws;
        unsigned int* ctr = (unsigned int*)((char*)d_ws + (size_t)B * 8);
        hipMemsetAsync(d_ws, 0, need, stream);
        const int rowGroups = (B + R - 1) / R;
        fused_sampler_kernel<<<rowGroups * S, 256, smem, stream>>>(
            logits, temps, expo, out, keys, ctr, B, V, S, segLen, R);
    } else {
        row_argmax_kernel<<<B, 1024, 0, stream>>>(logits, temps, expo, out, V);
    }
}

// Round 5
// 26.040 us; speedup vs baseline: 2.2249x; 2.2249x over previous
//
#include <hip/hip_runtime.h>
#include <hip/hip_bf16.h>
#include <math.h>

#define EPS 1e-10f
#define LOG2E 1.4426950408889634f

typedef float floatx4 __attribute__((ext_vector_type(4)));

// One block per row, 1024 threads (16 waves), contiguous row streaming.
// Scores (monotone-equivalent to reference's softmax(l/t)/(E+eps)):
//   greedy (t==0): l[j]
//   sampled:       l[j]*(log2e/t) - log2(E[j]+EPS)   [v_log_f32, 1 inst]
// Per-row argmax with first-occurrence tie-break, matching jnp.argmax.
__global__ __launch_bounds__(1024) void sampler_row_kernel(
    const float* __restrict__ logits,
    const float* __restrict__ temps,
    const float* __restrict__ expo,
    int* __restrict__ out, int V) {

    const int row = blockIdx.x;
    const float t = temps[row];                  // block-uniform
    const bool greedy = (t == 0.0f);
    const float c = greedy ? 1.0f : (LOG2E / t);

    const float*   rl  = logits + (size_t)row * (size_t)V;
    const floatx4* rl4 = reinterpret_cast<const floatx4*>(rl);
    const floatx4* e4  = reinterpret_cast<const floatx4*>(expo);

    float best = -INFINITY;
    int   bidx = 0x7fffffff;

    const int nvec = V >> 2;

    if (greedy) {
        for (int i = threadIdx.x; i < nvec; i += 1024) {
            floatx4 l = rl4[i];
            int base = i << 2;
            if (l.x > best) { best = l.x; bidx = base;     }
            if (l.y > best) { best = l.y; bidx = base + 1; }
            if (l.z > best) { best = l.z; bidx = base + 2; }
            if (l.w > best) { best = l.w; bidx = base + 3; }
        }
    } else {
        for (int i = threadIdx.x; i < nvec; i += 1024) {
            floatx4 l = rl4[i];
            floatx4 e = e4[i];
            float s0 = fmaf(l.x, c, -__builtin_amdgcn_logf(e.x + EPS));
            float s1 = fmaf(l.y, c, -__builtin_amdgcn_logf(e.y + EPS));
            float s2 = fmaf(l.z, c, -__builtin_amdgcn_logf(e.z + EPS));
            float s3 = fmaf(l.w, c, -__builtin_amdgcn_logf(e.w + EPS));
            int base = i << 2;
            if (s0 > best) { best = s0; bidx = base;     }
            if (s1 > best) { best = s1; bidx = base + 1; }
            if (s2 > best) { best = s2; bidx = base + 2; }
            if (s3 > best) { best = s3; bidx = base + 3; }
        }
    }

    // Scalar tail (V % 4 != 0); zero iterations for V = 128000.
    for (int j = (nvec << 2) + threadIdx.x; j < V; j += 1024) {
        float s = greedy ? rl[j]
                         : fmaf(rl[j], c, -__builtin_amdgcn_logf(expo[j] + EPS));
        if (s > best) { best = s; bidx = j; }
    }

    // Wave reduce (64 lanes on CDNA). Prefer lower index on exact ties.
    #pragma unroll
    for (int off = 32; off >= 1; off >>= 1) {
        float ov = __shfl_down(best, off);
        int   oi = __shfl_down(bidx, off);
        if (ov > best || (ov == best && oi < bidx)) { best = ov; bidx = oi; }
    }

    // Cross-wave reduce via LDS (16 waves).
    __shared__ float sv[16];
    __shared__ int   si[16];
    const int wid  = threadIdx.x >> 6;
    const int lane = threadIdx.x & 63;
    if (lane == 0) { sv[wid] = best; si[wid] = bidx; }
    __syncthreads();

    if (wid == 0) {
        best = (lane < 16) ? sv[lane] : -INFINITY;
        bidx = (lane < 16) ? si[lane] : 0x7fffffff;
        #pragma unroll
        for (int off = 8; off >= 1; off >>= 1) {
            float ov = __shfl_down(best, off);
            int   oi = __shfl_down(bidx, off);
            if (ov > best || (ov == best && oi < bidx)) { best = ov; bidx = oi; }
        }
        if (lane == 0) out[row] = bidx;
    }
}

extern "C" void kernel_launch(void* const* d_in, const int* in_sizes, int n_in,
                              void* d_out, int out_size, void* d_ws, size_t ws_size,
                              hipStream_t stream) {
    const float* logits = (const float*)d_in[0];
    const float* temps  = (const float*)d_in[1];
    const float* expo   = (const float*)d_in[2];
    int*         out    = (int*)d_out;

    const int B = in_sizes[1];
    const int V = in_sizes[2];

    sampler_row_kernel<<<B, 1024, 0, stream>>>(logits, temps, expo, out, V);
}